// Round 11
// baseline (172.698 us; speedup 1.0000x reference)
//
#include <hip/hip_runtime.h>
#include <stdint.h>

#define NH 8
#define NB 8
#define NN 1024
#define ND 128
#define NK 16
#define NF (NB*NN)          // 8192 flat (b,n) rows
#define C2EXP 0.36067376022224085f   // (1/sqrt(16)) * log2(e), folded into Q proj
#define LSTR 136            // LDS row stride (bf16 elems): 272 B = 17*16 B

typedef float f32x16 __attribute__((ext_vector_type(16)));
typedef short bf16x8 __attribute__((ext_vector_type(8)));

__device__ __forceinline__ uint16_t f2bf(float f){
  uint32_t x = __float_as_uint(f);
  uint32_t r = (x + 0x7fffu + ((x>>16)&1u)) >> 16;   // RNE
  return (uint16_t)r;
}

// exp2 on the full-rate FMA pipe (avoids the transcendental unit, which the
// R8-R10 invariance suggests is the saturated shared resource).
// deg-2 minimax on f in [-0.5,0.5], rel err ~7e-5 << bf16 eps.
// ldexp handles large-negative scores (underflow to 0) safely.
__device__ __forceinline__ float poly_exp2(float x){
  float i = __builtin_rintf(x);                       // v_rndne_f32
  float f = x - i;
  float P = __builtin_fmaf(f, __builtin_fmaf(f, 0.22606716f, 0.69583354f),
                           0.99992520f);
  return __builtin_ldexpf(P, (int)i);                 // v_cvt_i32 + v_ldexp_f32
}

// pack mask n-major: packN[row=b*NN+q][t] bit j = mask[b][q][t*32+j].
// Also writes the 1024-elem bf16 ones row used as V^T row 16.
__global__ __launch_bounds__(256) void pack_kernel(const int* __restrict__ mask,
                                                   uint32_t* __restrict__ packN,
                                                   uint16_t* __restrict__ onesw){
  if (blockIdx.x == 0) {
    for (int i = threadIdx.x; i < 1024; i += 256) onesw[i] = 0x3F80;  // 1.0bf
  }
  const int w = threadIdx.x >> 6, lane = threadIdx.x & 63;
  const int row = blockIdx.x*4 + w;          // 0..8191
  const int* mp = mask + (size_t)row*NN;
  uint32_t* dst = packN + (size_t)row*32;
  for (int wq = 0; wq < 16; ++wq) {
    int v = mp[wq*64 + lane];
    unsigned long long bal = __ballot(v != 0);
    if (lane == 0) { dst[wq*2] = (uint32_t)bal; dst[wq*2+1] = (uint32_t)(bal>>32); }
  }
}

struct ProjArgs { const float* x[8]; const float* w[8]; };

// MFMA projection: block = 128 rows x one projection p (128 out cols).
// fp32 x,W in; bf16 out. Q/K -> [h][row][k]; V (p=2,5,7) -> VT [hb][k][n'],
// with n' = mu(n): within each 16-group swap quartets 1<->2 (involution).
// mu makes the attention P-pack directly usable as the PV B-fragment.
// Q projections (p=0,3) pre-scaled by C2EXP so attention exp is raw exp2.
__global__ __launch_bounds__(256) void proj_kernel(ProjArgs args, uint16_t* ws){
  __shared__ __align__(16) uint16_t WT[128*LSTR];  // [n=h*16+k][d]
  __shared__ __align__(16) uint16_t S[128*LSTR];   // epilogue staging
  const int p = blockIdx.y;
  const int rb = blockIdx.x;           // row-block of 128
  const int tid = threadIdx.x;

  const float4* w4 = (const float4*)args.w[p];     // [h][d][k] fp32
  #pragma unroll
  for (int i = 0; i < 16; ++i) {
    int e4 = i*256 + tid;              // coalesced float4
    float4 f = w4[e4];
    int e = e4*4;
    int h = e >> 11, d = (e >> 4) & 127, k = e & 15;   // k in {0,4,8,12}
    uint16_t* wr = &WT[(h*16 + k)*LSTR + d];
    wr[0*LSTR] = f2bf(f.x); wr[1*LSTR] = f2bf(f.y);
    wr[2*LSTR] = f2bf(f.z); wr[3*LSTR] = f2bf(f.w);
  }
  __syncthreads();

  const int wave = tid >> 6, lane = tid & 63;
  const int l5 = lane >> 5, lm = lane & 31;
  const int r0 = rb*128 + wave*32;
  const float* xrow = args.x[p] + (size_t)(r0 + lm)*ND + l5*8;

  bf16x8 afr[8];
  #pragma unroll
  for (int kt = 0; kt < 8; ++kt) {
    float4 f0 = *(const float4*)(xrow + kt*16);
    float4 f1 = *(const float4*)(xrow + kt*16 + 4);
    bf16x8 a;
    a[0]=f2bf(f0.x); a[1]=f2bf(f0.y); a[2]=f2bf(f0.z); a[3]=f2bf(f0.w);
    a[4]=f2bf(f1.x); a[5]=f2bf(f1.y); a[6]=f2bf(f1.z); a[7]=f2bf(f1.w);
    afr[kt] = a;
  }

  const bool tr = (p==2)|(p==5)|(p==7);
  const float qsc = (p==0 || p==3) ? C2EXP : 1.0f;
  #pragma unroll
  for (int nt = 0; nt < 4; ++nt) {
    f32x16 acc;
    #pragma unroll
    for (int i = 0; i < 16; ++i) acc[i] = 0.f;
    #pragma unroll
    for (int kt = 0; kt < 8; ++kt) {
      bf16x8 b = *(const bf16x8*)(&WT[(nt*32 + lm)*LSTR + kt*16 + l5*8]);
      acc = __builtin_amdgcn_mfma_f32_32x32x16_bf16(afr[kt], b, acc, 0, 0, 0);
    }
    #pragma unroll
    for (int i = 0; i < 16; ++i) {
      int r = wave*32 + (i&3) + 8*(i>>2) + 4*l5;   // local row 0..127
      int c = nt*32 + lm;
      if (tr) {
        int t2 = (r>>2)&3;                         // mu permutation on n
        int rp = (t2==1 || t2==2) ? (r^12) : r;
        S[c*LSTR + rp] = f2bf(acc[i]);
      } else {
        S[r*LSTR + c] = f2bf(acc[i]*qsc);
      }
    }
  }
  __syncthreads();

  uint16_t* dst = ws + (size_t)p*((size_t)NH*NF*NK);
  if (!tr) {
    #pragma unroll
    for (int it = 0; it < 8; ++it) {
      int c = it*256 + tid;            // 2048 chunks of 8 elems
      int row = c >> 4, cg = c & 15;
      bf16x8 v = *(const bf16x8*)(&S[row*LSTR + cg*8]);
      int h = cg >> 1, k8 = cg & 1;
      *(bf16x8*)(dst + ((size_t)h*NF + rb*128 + row)*NK + k8*8) = v;
    }
  } else {
    const int b = rb >> 3, nb = (rb & 7)*128;
    #pragma unroll
    for (int it = 0; it < 8; ++it) {
      int c = it*256 + tid;
      int col = c >> 4, ng = c & 15;   // col = h*16+k
      bf16x8 v = *(const bf16x8*)(&S[col*LSTR + ng*8]);
      int h = col >> 4, k = col & 15;
      *(bf16x8*)(dst + ((size_t)(h*NB + b)*NK + k)*NN + nb + ng*8) = v;
    }
  }
}

// One attention stream over this wave's 16 n-tiles (n-half nh).
// S^T form: lane = query col. No max subtraction. O^T = V^T(A) x P^T(B);
// V^T mu-permuted in n so packed exp dwords ARE the B-fragment.
// vbase: per-lane V^T row ptr (lane 16 -> ones row => L in O[reg 8]).
// Depth-1 software pipeline: V loads + QK MFMA for tile t+1 issue before
// the exp/pack/PV of tile t.
template<bool MASKED>
__device__ __forceinline__ void attn_stream(
    const uint4* __restrict__ kbuf, bf16x8 aq,
    const uint16_t* __restrict__ vbase, const uint4* __restrict__ pmw4,
    int nh, int l5, int lm, f32x16& O)
{
  f32x16 Z;
  #pragma unroll
  for (int i = 0; i < 16; ++i) Z[i] = 0.f;

  uint32_t mw[16];
  if (MASKED) {
    uint4 m0 = pmw4[nh*4+0], m1 = pmw4[nh*4+1];
    uint4 m2 = pmw4[nh*4+2], m3 = pmw4[nh*4+3];
    mw[0]=m0.x; mw[1]=m0.y; mw[2]=m0.z; mw[3]=m0.w;
    mw[4]=m1.x; mw[5]=m1.y; mw[6]=m1.z; mw[7]=m1.w;
    mw[8]=m2.x; mw[9]=m2.y; mw[10]=m2.z; mw[11]=m2.w;
    mw[12]=m3.x; mw[13]=m3.y; mw[14]=m3.z; mw[15]=m3.w;
  }

  const int base_n = nh*512;
  const bool vload = (lm < 17);

  bf16x8 av1, av2, av1n, av2n;
  #pragma unroll
  for (int i = 0; i < 8; ++i) { av1[i]=0; av2[i]=0; av1n[i]=0; av2n[i]=0; }
  if (vload) {
    const uint16_t* vp = vbase + base_n + l5*8;
    av1 = *(const bf16x8*)(vp);
    av2 = *(const bf16x8*)(vp + 16);
  }
  f32x16 Stc = __builtin_amdgcn_mfma_f32_32x32x16_bf16(
      *(const bf16x8*)(&kbuf[l5*1024 + base_n + lm]), aq, Z, 0, 0, 0);

  #pragma unroll
  for (int t = 0; t < 16; ++t) {
    f32x16 Stn;
    if (t < 15) {
      const int n1 = base_n + (t+1)*32;
      if (vload) {
        const uint16_t* vp = vbase + n1 + l5*8;
        av1n = *(const bf16x8*)(vp);
        av2n = *(const bf16x8*)(vp + 16);
      }
      Stn = __builtin_amdgcn_mfma_f32_32x32x16_bf16(
          *(const bf16x8*)(&kbuf[l5*1024 + n1 + lm]), aq, Z, 0, 0, 0);
    }

    const uint32_t mws = MASKED ? (mw[t] >> (4*l5)) : 0u;
    float p[16];
    #pragma unroll
    for (int i = 0; i < 16; ++i) {
      float pv = poly_exp2(Stc[i]);            // Q pre-scaled by C2EXP
      if (MASKED && ((mws >> ((i&3) + 8*(i>>2))) & 1u)) pv = 0.f;
      p[i] = pv;
    }
    // truncate-pack pairs; via mu-permuted V^T these are B-frags directly
    union { uint32_t u[4]; bf16x8 v; } B1, B2;
    #pragma unroll
    for (int k = 0; k < 4; ++k) {
      B1.u[k] = __builtin_amdgcn_perm(__float_as_uint(p[2*k+1]),
                                      __float_as_uint(p[2*k]),   0x07060302u);
      B2.u[k] = __builtin_amdgcn_perm(__float_as_uint(p[2*k+9]),
                                      __float_as_uint(p[2*k+8]), 0x07060302u);
    }
    O = __builtin_amdgcn_mfma_f32_32x32x16_bf16(av1, B1.v, O, 0, 0, 0);
    O = __builtin_amdgcn_mfma_f32_32x32x16_bf16(av2, B2.v, O, 0, 0, 0);

    if (t < 15) { Stc = Stn; av1 = av1n; av2 = av2n; }
  }
}

// Fused attention: z=0 -> node (masked nn + nc, summed); z=1 -> color.
// 512 threads = 8 waves: wave = qt(4) x nh(2); block = 128 q-rows of (h,b).
// LDS: 32 KB kbuf only; combine buffer aliases kbuf (fenced by barriers).
// heads out: [row=b*NN+q][h*16+v] bf16.
__global__ __launch_bounds__(512, 4) void attn_kernel(
    const uint16_t* __restrict__ Qn_, const uint16_t* __restrict__ K1n,
    const uint16_t* __restrict__ V1n, const uint16_t* __restrict__ K2n,
    const uint16_t* __restrict__ V2n,
    const uint16_t* __restrict__ Qc_, const uint16_t* __restrict__ K1c,
    const uint16_t* __restrict__ V1c,
    const uint32_t* __restrict__ packN, const uint16_t* __restrict__ onesb,
    uint16_t* __restrict__ hn_, uint16_t* __restrict__ hc_)
{
  __shared__ uint4 kbuf[2048];               // 32 KB, plane-split; aliased below
  const bool dual = (blockIdx.z == 0);
  const uint16_t* Q   = dual ? Qn_ : Qc_;
  const uint16_t* K1  = dual ? K1n : K1c;
  uint16_t* outp      = dual ? hn_ : hc_;

  const int hb = blockIdx.y;
  const int h = hb >> 3, b = hb & 7;
  const size_t base = ((size_t)h*NF + (size_t)b*NN)*NK;
  const int tid = threadIdx.x;

  const uint4* k1 = (const uint4*)(K1 + base);
  for (int i = tid; i < 2048; i += 512)
    kbuf[(i & 1)*1024 + (i >> 1)] = k1[i];
  __syncthreads();

  const int wave = tid >> 6, lane = tid & 63;
  const int l5 = lane >> 5, lm = lane & 31;
  const int qt = wave & 3, nh = wave >> 2;
  const int q = blockIdx.x*128 + qt*32 + lm;

  const bf16x8 aq = *(const bf16x8*)(Q + base + (size_t)q*NK + l5*8);
  const uint4* pmw4 = (const uint4*)(packN + ((size_t)b*NN + q)*32);

  const uint16_t* VT1 = (dual ? V1n : V1c) + (size_t)hb*(NK*NN);
  const uint16_t* vb1 = (lm < 16) ? (VT1 + (size_t)lm*NN) : onesb;

  f32x16 O1, O2;
  #pragma unroll
  for (int i = 0; i < 16; ++i) { O1[i] = 0.f; O2[i] = 0.f; }

  if (dual) {
    attn_stream<true>(kbuf, aq, vb1, pmw4, nh, l5, lm, O1);
    __syncthreads();
    const uint4* k2 = (const uint4*)(K2n + base);
    for (int i = tid; i < 2048; i += 512)
      kbuf[(i & 1)*1024 + (i >> 1)] = k2[i];
    __syncthreads();
    const uint16_t* VT2 = V2n + (size_t)hb*(NK*NN);
    const uint16_t* vb2 = (lm < 16) ? (VT2 + (size_t)lm*NN) : onesb;
    attn_stream<false>(kbuf, aq, vb2, nullptr, nh, l5, lm, O2);
  } else {
    attn_stream<false>(kbuf, aq, vb1, nullptr, nh, l5, lm, O1);
  }

  // L = O[reg 8] (row v=16, ones): l5=0 lanes hold it, l5=1 hold 0
  float L1 = O1[8] + __shfl_xor(O1[8], 32, 64);
  float L2 = O2[8] + __shfl_xor(O2[8], 32, 64);

  __syncthreads();                           // all kbuf reads done: safe to alias
  float* cw = ((float*)kbuf) + ((size_t)(qt*2 + l5)*32 + lm)*18;   // 18 KB < 32 KB
  if (nh == 1) {
    #pragma unroll
    for (int i = 0; i < 8; ++i) cw[i] = O1[i];
    if (dual) {
      #pragma unroll
      for (int i = 0; i < 8; ++i) cw[8+i] = O2[i];
    }
    cw[16] = L1; cw[17] = L2;
  }
  __syncthreads();
  if (nh == 0) {
    const float l1 = L1 + cw[16];
    const float i1 = (l1 > 0.f) ? 1.f/l1 : 0.f;
    float i2 = 0.f;
    if (dual) { const float l2 = L2 + cw[17]; i2 = (l2 > 0.f) ? 1.f/l2 : 0.f; }
    uint32_t w[4];
    #pragma unroll
    for (int k = 0; k < 4; ++k) {
      float va = (O1[2*k]   + cw[2*k])  *i1;
      float vb = (O1[2*k+1] + cw[2*k+1])*i1;
      if (dual) { va += (O2[2*k] + cw[8+2*k])*i2; vb += (O2[2*k+1] + cw[8+2*k+1])*i2; }
      w[k] = ((uint32_t)f2bf(vb) << 16) | f2bf(va);
    }
    uint16_t* hp = outp + ((size_t)b*NN + q)*128 + h*16 + l5*4;
    *(uint2*)(hp)     = make_uint2(w[0], w[1]);   // v = l5*4 .. +3
    *(uint2*)(hp + 8) = make_uint2(w[2], w[3]);   // v = 8+l5*4 .. +3
  }
}

// MFMA out-projection: out[row][e] = sum_c heads[row][c] * Wout[c][e]; fp32 out.
// 64 rows/block; wave = (rowhalf rt, nt-pair nh2).
__global__ __launch_bounds__(256) void outproj_kernel(
    const uint16_t* __restrict__ hn, const uint16_t* __restrict__ hc,
    const float* __restrict__ wn, const float* __restrict__ wc,
    float* __restrict__ out)
{
  __shared__ __align__(16) uint16_t WT[128*LSTR];  // [e][c]
  const int s = blockIdx.y;            // 0 node, 1 color
  const int rb = blockIdx.x;           // 128 blocks of 64 rows
  const int tid = threadIdx.x;
  const float* wsrc = s ? wc : wn;     // [c=h*16+v][e] row-major 128x128
  const float4* w4 = (const float4*)wsrc;
  #pragma unroll
  for (int i = 0; i < 16; ++i) {
    int e4 = i*256 + tid;
    float4 f = w4[e4];
    int e = e4*4;
    int c = e >> 7, col = e & 127;     // 4 consecutive cols, same c
    uint16_t* wr = &WT[col*LSTR + c];
    wr[0*LSTR] = f2bf(f.x); wr[1*LSTR] = f2bf(f.y);
    wr[2*LSTR] = f2bf(f.z); wr[3*LSTR] = f2bf(f.w);
  }
  __syncthreads();

  const int wave = tid >> 6, lane = tid & 63;
  const int l5 = lane >> 5, lm = lane & 31;
  const int rt = wave & 1, nh2 = wave >> 1;
  const int r0 = rb*64 + rt*32;
  const uint16_t* hp = (s ? hc : hn) + (size_t)(r0 + lm)*128 + l5*8;
  bf16x8 afr[8];
  #pragma unroll
  for (int kt = 0; kt < 8; ++kt) afr[kt] = *(const bf16x8*)(hp + kt*16);

  float* dst = out + (size_t)s*((size_t)NF*ND) + (size_t)r0*ND;
  #pragma unroll
  for (int nt2 = 0; nt2 < 2; ++nt2) {
    const int nt = nh2*2 + nt2;
    f32x16 acc;
    #pragma unroll
    for (int i = 0; i < 16; ++i) acc[i] = 0.f;
    #pragma unroll
    for (int kt = 0; kt < 8; ++kt) {
      bf16x8 b = *(const bf16x8*)(&WT[(nt*32 + lm)*LSTR + kt*16 + l5*8]);
      acc = __builtin_amdgcn_mfma_f32_32x32x16_bf16(afr[kt], b, acc, 0, 0, 0);
    }
    #pragma unroll
    for (int i = 0; i < 16; ++i) {
      int r = (i&3) + 8*(i>>2) + 4*l5;
      dst[(size_t)r*ND + nt*32 + lm] = acc[i];
    }
  }
}

extern "C" void kernel_launch(void* const* d_in, const int* in_sizes, int n_in,
                              void* d_out, int out_size, void* d_ws, size_t ws_size,
                              hipStream_t stream)
{
  const float* q_n = (const float*)d_in[0];
  const float* q_c = (const float*)d_in[1];
  const int* mask = (const int*)d_in[2];
  const float* W[10];
  for (int i = 0; i < 10; ++i) W[i] = (const float*)d_in[3+i];
  // W[0]=W_query_n W[1]=W_key_nn W[2]=W_val_nn W[3]=W_key_c W[4]=W_val_c
  // W[5]=W_query_c W[6]=W_key_n  W[7]=W_val_n  W[8]=W_out_node W[9]=W_out_color

  uint16_t* ws16 = (uint16_t*)d_ws;
  const size_t PE = (size_t)NH*NF*NK;   // 1,048,576 elements per slot
  uint16_t* Qc   = ws16 + 0*PE;
  uint16_t* Kn   = ws16 + 1*PE;
  uint16_t* VTn  = ws16 + 2*PE;   // [hb][16][1024], n mu-permuted
  uint16_t* Qn   = ws16 + 3*PE;
  uint16_t* Knn  = ws16 + 4*PE;
  uint16_t* VTnn = ws16 + 5*PE;
  uint16_t* Knc  = ws16 + 6*PE;
  uint16_t* VTnc = ws16 + 7*PE;
  uint16_t* heads_node = ws16 + 8*PE;   // [row][h*16+v] bf16
  uint32_t* packN   = (uint32_t*)(ws16 + 9*PE);   // 1 MB
  uint16_t* heads_c = ws16 + 10*PE;     // separate slot: attn z-slices unordered
  uint16_t* onesb   = ws16 + 11*PE;     // 1024 bf16 ones (V^T row 16)

  pack_kernel<<<2048, 256, 0, stream>>>(mask, packN, onesb);

  ProjArgs pa;
  pa.x[0]=q_c; pa.w[0]=W[5];  // Q_c (pre-scaled C2EXP)
  pa.x[1]=q_n; pa.w[1]=W[6];  // K_n
  pa.x[2]=q_n; pa.w[2]=W[7];  // V_n  (transposed, mu-permuted)
  pa.x[3]=q_n; pa.w[3]=W[0];  // Q_n (pre-scaled C2EXP)
  pa.x[4]=q_n; pa.w[4]=W[1];  // K_nn
  pa.x[5]=q_n; pa.w[5]=W[2];  // V_nn (transposed, mu-permuted)
  pa.x[6]=q_c; pa.w[6]=W[3];  // K_nc
  pa.x[7]=q_c; pa.w[7]=W[4];  // V_nc (transposed, mu-permuted)
  proj_kernel<<<dim3(64, 8), 256, 0, stream>>>(pa, ws16);

  attn_kernel<<<dim3(8, 64, 2), 512, 0, stream>>>(
      Qn, Knn, VTnn, Knc, VTnc, Qc, Kn, VTn, packN, onesb,
      heads_node, heads_c);

  outproj_kernel<<<dim3(128, 2), 256, 0, stream>>>(heads_node, heads_c,
                                                   W[8], W[9], (float*)d_out);
}

// Round 12
// 167.408 us; speedup vs baseline: 1.0316x; 1.0316x over previous
//
#include <hip/hip_runtime.h>
#include <stdint.h>

#define NH 8
#define NB 8
#define NN 1024
#define ND 128
#define NK 16
#define NF (NB*NN)          // 8192 flat (b,n) rows
#define C2EXP 0.36067376022224085f   // (1/sqrt(16)) * log2(e), folded into Q proj
#define LSTR 136            // LDS row stride (bf16 elems): 272 B = 17*16 B

typedef float f32x16 __attribute__((ext_vector_type(16)));
typedef short bf16x8 __attribute__((ext_vector_type(8)));

__device__ __forceinline__ uint16_t f2bf(float f){
  uint32_t x = __float_as_uint(f);
  uint32_t r = (x + 0x7fffu + ((x>>16)&1u)) >> 16;   // RNE
  return (uint16_t)r;
}
__device__ __forceinline__ float fast_exp2(float x){
#if __has_builtin(__builtin_amdgcn_exp2f)
  return __builtin_amdgcn_exp2f(x);
#else
  return exp2f(x);
#endif
}

// pack mask n-major: packN[row=b*NN+q][t] bit j = mask[b][q][t*32+j].
// Also writes the 1024-elem bf16 ones row used as V^T row 16.
__global__ __launch_bounds__(256) void pack_kernel(const int* __restrict__ mask,
                                                   uint32_t* __restrict__ packN,
                                                   uint16_t* __restrict__ onesw){
  if (blockIdx.x == 0) {
    for (int i = threadIdx.x; i < 1024; i += 256) onesw[i] = 0x3F80;  // 1.0bf
  }
  const int w = threadIdx.x >> 6, lane = threadIdx.x & 63;
  const int row = blockIdx.x*4 + w;          // 0..8191
  const int* mp = mask + (size_t)row*NN;
  uint32_t* dst = packN + (size_t)row*32;
  for (int wq = 0; wq < 16; ++wq) {
    int v = mp[wq*64 + lane];
    unsigned long long bal = __ballot(v != 0);
    if (lane == 0) { dst[wq*2] = (uint32_t)bal; dst[wq*2+1] = (uint32_t)(bal>>32); }
  }
}

struct ProjArgs { const float* x[8]; const float* w[8]; };

// MFMA projection: block = 128 rows x one projection p (128 out cols).
// fp32 x,W in; bf16 out. Q/K -> [h][row][k]; V (p=2,5,7) -> VT [hb][k][n'],
// with n' = mu(n): within each 16-group swap quartets 1<->2 (involution).
// mu makes the attention P-pack directly usable as the PV B-fragment.
// Q projections (p=0,3) pre-scaled by C2EXP so attention exp is raw exp2.
__global__ __launch_bounds__(256) void proj_kernel(ProjArgs args, uint16_t* ws){
  __shared__ __align__(16) uint16_t WT[128*LSTR];  // [n=h*16+k][d]
  __shared__ __align__(16) uint16_t S[128*LSTR];   // epilogue staging
  const int p = blockIdx.y;
  const int rb = blockIdx.x;           // row-block of 128
  const int tid = threadIdx.x;

  const float4* w4 = (const float4*)args.w[p];     // [h][d][k] fp32
  #pragma unroll
  for (int i = 0; i < 16; ++i) {
    int e4 = i*256 + tid;              // coalesced float4
    float4 f = w4[e4];
    int e = e4*4;
    int h = e >> 11, d = (e >> 4) & 127, k = e & 15;   // k in {0,4,8,12}
    uint16_t* wr = &WT[(h*16 + k)*LSTR + d];
    wr[0*LSTR] = f2bf(f.x); wr[1*LSTR] = f2bf(f.y);
    wr[2*LSTR] = f2bf(f.z); wr[3*LSTR] = f2bf(f.w);
  }
  __syncthreads();

  const int wave = tid >> 6, lane = tid & 63;
  const int l5 = lane >> 5, lm = lane & 31;
  const int r0 = rb*128 + wave*32;
  const float* xrow = args.x[p] + (size_t)(r0 + lm)*ND + l5*8;

  bf16x8 afr[8];
  #pragma unroll
  for (int kt = 0; kt < 8; ++kt) {
    float4 f0 = *(const float4*)(xrow + kt*16);
    float4 f1 = *(const float4*)(xrow + kt*16 + 4);
    bf16x8 a;
    a[0]=f2bf(f0.x); a[1]=f2bf(f0.y); a[2]=f2bf(f0.z); a[3]=f2bf(f0.w);
    a[4]=f2bf(f1.x); a[5]=f2bf(f1.y); a[6]=f2bf(f1.z); a[7]=f2bf(f1.w);
    afr[kt] = a;
  }

  const bool tr = (p==2)|(p==5)|(p==7);
  const float qsc = (p==0 || p==3) ? C2EXP : 1.0f;
  #pragma unroll
  for (int nt = 0; nt < 4; ++nt) {
    f32x16 acc;
    #pragma unroll
    for (int i = 0; i < 16; ++i) acc[i] = 0.f;
    #pragma unroll
    for (int kt = 0; kt < 8; ++kt) {
      bf16x8 b = *(const bf16x8*)(&WT[(nt*32 + lm)*LSTR + kt*16 + l5*8]);
      acc = __builtin_amdgcn_mfma_f32_32x32x16_bf16(afr[kt], b, acc, 0, 0, 0);
    }
    #pragma unroll
    for (int i = 0; i < 16; ++i) {
      int r = wave*32 + (i&3) + 8*(i>>2) + 4*l5;   // local row 0..127
      int c = nt*32 + lm;
      if (tr) {
        int t2 = (r>>2)&3;                         // mu permutation on n
        int rp = (t2==1 || t2==2) ? (r^12) : r;
        S[c*LSTR + rp] = f2bf(acc[i]);
      } else {
        S[r*LSTR + c] = f2bf(acc[i]*qsc);
      }
    }
  }
  __syncthreads();

  uint16_t* dst = ws + (size_t)p*((size_t)NH*NF*NK);
  if (!tr) {
    #pragma unroll
    for (int it = 0; it < 8; ++it) {
      int c = it*256 + tid;            // 2048 chunks of 8 elems
      int row = c >> 4, cg = c & 15;
      bf16x8 v = *(const bf16x8*)(&S[row*LSTR + cg*8]);
      int h = cg >> 1, k8 = cg & 1;
      *(bf16x8*)(dst + ((size_t)h*NF + rb*128 + row)*NK + k8*8) = v;
    }
  } else {
    const int b = rb >> 3, nb = (rb & 7)*128;
    #pragma unroll
    for (int it = 0; it < 8; ++it) {
      int c = it*256 + tid;
      int col = c >> 4, ng = c & 15;   // col = h*16+k
      bf16x8 v = *(const bf16x8*)(&S[col*LSTR + ng*8]);
      int h = col >> 4, k = col & 15;
      *(bf16x8*)(dst + ((size_t)(h*NB + b)*NK + k)*NN + nb + ng*8) = v;
    }
  }
}

// One attention stream over this wave's 16 n-tiles (n-half nh).
// S^T form: lane = query col. No max subtraction. O^T = V^T(A) x P^T(B);
// V^T mu-permuted in n so packed exp dwords ARE the B-fragment.
// vbase: per-lane V^T row ptr (lane 16 -> ones row => L in O[reg 8]).
// Depth-1 pipeline: V loads + QK MFMA for tile t+1 before exp/pack/PV of t.
template<bool MASKED>
__device__ __forceinline__ void attn_stream(
    const uint4* __restrict__ kbuf, bf16x8 aq,
    const uint16_t* __restrict__ vbase, const uint4* __restrict__ pmw4,
    int nh, int l5, int lm, f32x16& O)
{
  f32x16 Z;
  #pragma unroll
  for (int i = 0; i < 16; ++i) Z[i] = 0.f;

  uint32_t mw[16];
  if (MASKED) {
    uint4 m0 = pmw4[nh*4+0], m1 = pmw4[nh*4+1];
    uint4 m2 = pmw4[nh*4+2], m3 = pmw4[nh*4+3];
    mw[0]=m0.x; mw[1]=m0.y; mw[2]=m0.z; mw[3]=m0.w;
    mw[4]=m1.x; mw[5]=m1.y; mw[6]=m1.z; mw[7]=m1.w;
    mw[8]=m2.x; mw[9]=m2.y; mw[10]=m2.z; mw[11]=m2.w;
    mw[12]=m3.x; mw[13]=m3.y; mw[14]=m3.z; mw[15]=m3.w;
  }

  const int base_n = nh*512;
  const bool vload = (lm < 17);

  bf16x8 av1, av2, av1n, av2n;
  #pragma unroll
  for (int i = 0; i < 8; ++i) { av1[i]=0; av2[i]=0; av1n[i]=0; av2n[i]=0; }
  if (vload) {
    const uint16_t* vp = vbase + base_n + l5*8;
    av1 = *(const bf16x8*)(vp);
    av2 = *(const bf16x8*)(vp + 16);
  }
  f32x16 Stc = __builtin_amdgcn_mfma_f32_32x32x16_bf16(
      *(const bf16x8*)(&kbuf[l5*1024 + base_n + lm]), aq, Z, 0, 0, 0);

  #pragma unroll
  for (int t = 0; t < 16; ++t) {
    f32x16 Stn;
    if (t < 15) {
      const int n1 = base_n + (t+1)*32;
      if (vload) {
        const uint16_t* vp = vbase + n1 + l5*8;
        av1n = *(const bf16x8*)(vp);
        av2n = *(const bf16x8*)(vp + 16);
      }
      Stn = __builtin_amdgcn_mfma_f32_32x32x16_bf16(
          *(const bf16x8*)(&kbuf[l5*1024 + n1 + lm]), aq, Z, 0, 0, 0);
    }

    const uint32_t mws = MASKED ? (mw[t] >> (4*l5)) : 0u;
    float p[16];
    #pragma unroll
    for (int i = 0; i < 16; ++i) {
      float pv = fast_exp2(Stc[i]);            // Q pre-scaled by C2EXP
      if (MASKED && ((mws >> ((i&3) + 8*(i>>2))) & 1u)) pv = 0.f;
      p[i] = pv;
    }
    // truncate-pack pairs; via mu-permuted V^T these are B-frags directly
    union { uint32_t u[4]; bf16x8 v; } B1, B2;
    #pragma unroll
    for (int k = 0; k < 4; ++k) {
      B1.u[k] = __builtin_amdgcn_perm(__float_as_uint(p[2*k+1]),
                                      __float_as_uint(p[2*k]),   0x07060302u);
      B2.u[k] = __builtin_amdgcn_perm(__float_as_uint(p[2*k+9]),
                                      __float_as_uint(p[2*k+8]), 0x07060302u);
    }
    O = __builtin_amdgcn_mfma_f32_32x32x16_bf16(av1, B1.v, O, 0, 0, 0);
    O = __builtin_amdgcn_mfma_f32_32x32x16_bf16(av2, B2.v, O, 0, 0, 0);

    if (t < 15) { Stc = Stn; av1 = av1n; av2 = av2n; }
  }
}

// Attention, load-balanced: z in {0:nn-masked, 1:nc, 2:color} — 1536 UNIFORM
// blocks of 16 tiles/wave (fixes the R8-R10 dual/color 2:1 imbalance tail).
// nn and nc are normalized independently and summed later in outproj by
// linearity: (H1+H2)W = H1 W + H2 W.
// 512 threads = 8 waves: wave = qt(4) x nh(2); block = 128 q-rows of (h,b).
// LDS: 32 KB kbuf; combine buffer aliases kbuf (fenced by barriers).
// heads out: [row=b*NN+q][h*16+v] bf16, per-stream buffer.
__global__ __launch_bounds__(512, 4) void attn_kernel(
    const uint16_t* __restrict__ Qn_, const uint16_t* __restrict__ Qc_,
    const uint16_t* __restrict__ Knn, const uint16_t* __restrict__ VTnn,
    const uint16_t* __restrict__ Knc, const uint16_t* __restrict__ VTnc,
    const uint16_t* __restrict__ Knc_c, const uint16_t* __restrict__ VTc,
    const uint32_t* __restrict__ packN, const uint16_t* __restrict__ onesb,
    uint16_t* __restrict__ h_nn, uint16_t* __restrict__ h_nc,
    uint16_t* __restrict__ h_c)
{
  __shared__ uint4 kbuf[2048];               // 32 KB, plane-split; aliased below
  const int z = blockIdx.z;
  const bool masked = (z == 0);
  const uint16_t* Q  = (z == 2) ? Qc_ : Qn_;
  const uint16_t* K  = (z == 0) ? Knn : (z == 1) ? Knc : Knc_c;
  const uint16_t* VT = (z == 0) ? VTnn : (z == 1) ? VTnc : VTc;
  uint16_t* outp     = (z == 0) ? h_nn : (z == 1) ? h_nc : h_c;

  const int hb = blockIdx.y;
  const int h = hb >> 3, b = hb & 7;
  const size_t base = ((size_t)h*NF + (size_t)b*NN)*NK;
  const int tid = threadIdx.x;

  const uint4* kg = (const uint4*)(K + base);
  for (int i = tid; i < 2048; i += 512)
    kbuf[(i & 1)*1024 + (i >> 1)] = kg[i];
  __syncthreads();

  const int wave = tid >> 6, lane = tid & 63;
  const int l5 = lane >> 5, lm = lane & 31;
  const int qt = wave & 3, nh = wave >> 2;
  const int q = blockIdx.x*128 + qt*32 + lm;

  const bf16x8 aq = *(const bf16x8*)(Q + base + (size_t)q*NK + l5*8);
  const uint4* pmw4 = (const uint4*)(packN + ((size_t)b*NN + q)*32);

  const uint16_t* VTb = VT + (size_t)hb*(NK*NN);
  const uint16_t* vb = (lm < 16) ? (VTb + (size_t)lm*NN) : onesb;

  f32x16 O;
  #pragma unroll
  for (int i = 0; i < 16; ++i) O[i] = 0.f;

  if (masked) attn_stream<true >(kbuf, aq, vb, pmw4, nh, l5, lm, O);
  else        attn_stream<false>(kbuf, aq, vb, nullptr, nh, l5, lm, O);

  // L = O[reg 8] (row v=16, ones): l5=0 lanes hold it, l5=1 hold 0
  float L = O[8] + __shfl_xor(O[8], 32, 64);

  __syncthreads();                           // all kbuf reads done: safe to alias
  float* cw = ((float*)kbuf) + ((size_t)(qt*2 + l5)*32 + lm)*10;   // 10 KB < 32 KB
  if (nh == 1) {
    #pragma unroll
    for (int i = 0; i < 8; ++i) cw[i] = O[i];
    cw[8] = L;
  }
  __syncthreads();
  if (nh == 0) {
    const float l = L + cw[8];
    const float il = (l > 0.f) ? 1.f/l : 0.f;
    uint32_t w[4];
    #pragma unroll
    for (int k = 0; k < 4; ++k) {
      float va = (O[2*k]   + cw[2*k])  *il;
      float vb2 = (O[2*k+1] + cw[2*k+1])*il;
      w[k] = ((uint32_t)f2bf(vb2) << 16) | f2bf(va);
    }
    uint16_t* hp = outp + ((size_t)b*NN + q)*128 + h*16 + l5*4;
    *(uint2*)(hp)     = make_uint2(w[0], w[1]);   // v = l5*4 .. +3
    *(uint2*)(hp + 8) = make_uint2(w[2], w[3]);   // v = 8+l5*4 .. +3
  }
}

// MFMA out-projection; node stream sums h_nn + h_nc by MFMA linearity.
// out[row][e] = sum_c heads[row][c] * Wout[c][e]; fp32 out.
// 64 rows/block; wave = (rowhalf rt, nt-pair nh2).
__global__ __launch_bounds__(256) void outproj_kernel(
    const uint16_t* __restrict__ hnn, const uint16_t* __restrict__ hnc,
    const uint16_t* __restrict__ hc,
    const float* __restrict__ wn, const float* __restrict__ wc,
    float* __restrict__ out)
{
  __shared__ __align__(16) uint16_t WT[128*LSTR];  // [e][c]
  const int s = blockIdx.y;            // 0 node, 1 color
  const int rb = blockIdx.x;           // 128 blocks of 64 rows
  const int tid = threadIdx.x;
  const float* wsrc = s ? wc : wn;     // [c=h*16+v][e] row-major 128x128
  const float4* w4 = (const float4*)wsrc;
  #pragma unroll
  for (int i = 0; i < 16; ++i) {
    int e4 = i*256 + tid;
    float4 f = w4[e4];
    int e = e4*4;
    int c = e >> 7, col = e & 127;     // 4 consecutive cols, same c
    uint16_t* wr = &WT[col*LSTR + c];
    wr[0*LSTR] = f2bf(f.x); wr[1*LSTR] = f2bf(f.y);
    wr[2*LSTR] = f2bf(f.z); wr[3*LSTR] = f2bf(f.w);
  }
  __syncthreads();

  const int wave = tid >> 6, lane = tid & 63;
  const int l5 = lane >> 5, lm = lane & 31;
  const int rt = wave & 1, nh2 = wave >> 1;
  const int r0 = rb*64 + rt*32;
  const size_t hoff = (size_t)(r0 + lm)*128 + l5*8;
  const uint16_t* hp1 = (s ? hc : hnn) + hoff;
  const uint16_t* hp2 = hnc + hoff;     // node only
  bf16x8 afr1[8], afr2[8];
  #pragma unroll
  for (int kt = 0; kt < 8; ++kt) {
    afr1[kt] = *(const bf16x8*)(hp1 + kt*16);
    if (!s) afr2[kt] = *(const bf16x8*)(hp2 + kt*16);
  }

  float* dst = out + (size_t)s*((size_t)NF*ND) + (size_t)r0*ND;
  #pragma unroll
  for (int nt2 = 0; nt2 < 2; ++nt2) {
    const int nt = nh2*2 + nt2;
    f32x16 acc;
    #pragma unroll
    for (int i = 0; i < 16; ++i) acc[i] = 0.f;
    #pragma unroll
    for (int kt = 0; kt < 8; ++kt) {
      bf16x8 b = *(const bf16x8*)(&WT[(nt*32 + lm)*LSTR + kt*16 + l5*8]);
      acc = __builtin_amdgcn_mfma_f32_32x32x16_bf16(afr1[kt], b, acc, 0, 0, 0);
      if (!s)
        acc = __builtin_amdgcn_mfma_f32_32x32x16_bf16(afr2[kt], b, acc, 0, 0, 0);
    }
    #pragma unroll
    for (int i = 0; i < 16; ++i) {
      int r = (i&3) + 8*(i>>2) + 4*l5;
      dst[(size_t)r*ND + nt*32 + lm] = acc[i];
    }
  }
}

extern "C" void kernel_launch(void* const* d_in, const int* in_sizes, int n_in,
                              void* d_out, int out_size, void* d_ws, size_t ws_size,
                              hipStream_t stream)
{
  const float* q_n = (const float*)d_in[0];
  const float* q_c = (const float*)d_in[1];
  const int* mask = (const int*)d_in[2];
  const float* W[10];
  for (int i = 0; i < 10; ++i) W[i] = (const float*)d_in[3+i];
  // W[0]=W_query_n W[1]=W_key_nn W[2]=W_val_nn W[3]=W_key_c W[4]=W_val_c
  // W[5]=W_query_c W[6]=W_key_n  W[7]=W_val_n  W[8]=W_out_node W[9]=W_out_color

  uint16_t* ws16 = (uint16_t*)d_ws;
  const size_t PE = (size_t)NH*NF*NK;   // 1,048,576 elements per slot
  uint16_t* Qc   = ws16 + 0*PE;
  uint16_t* Kn   = ws16 + 1*PE;
  uint16_t* VTn  = ws16 + 2*PE;   // [hb][16][1024], n mu-permuted
  uint16_t* Qn   = ws16 + 3*PE;
  uint16_t* Knn  = ws16 + 4*PE;
  uint16_t* VTnn = ws16 + 5*PE;
  uint16_t* Knc  = ws16 + 6*PE;
  uint16_t* VTnc = ws16 + 7*PE;
  uint16_t* heads_nn = ws16 + 8*PE;     // [row][h*16+v] bf16 (nn, normalized)
  uint32_t* packN   = (uint32_t*)(ws16 + 9*PE);   // 1 MB
  uint16_t* heads_c  = ws16 + 10*PE;
  uint16_t* heads_nc = ws16 + 11*PE;    // (nc, normalized)
  uint16_t* onesb    = ws16 + 12*PE;    // 1024 bf16 ones (V^T row 16)

  pack_kernel<<<2048, 256, 0, stream>>>(mask, packN, onesb);

  ProjArgs pa;
  pa.x[0]=q_c; pa.w[0]=W[5];  // Q_c (pre-scaled C2EXP)
  pa.x[1]=q_n; pa.w[1]=W[6];  // K_n
  pa.x[2]=q_n; pa.w[2]=W[7];  // V_n  (transposed, mu-permuted)
  pa.x[3]=q_n; pa.w[3]=W[0];  // Q_n (pre-scaled C2EXP)
  pa.x[4]=q_n; pa.w[4]=W[1];  // K_nn
  pa.x[5]=q_n; pa.w[5]=W[2];  // V_nn (transposed, mu-permuted)
  pa.x[6]=q_c; pa.w[6]=W[3];  // K_nc
  pa.x[7]=q_c; pa.w[7]=W[4];  // V_nc (transposed, mu-permuted)
  proj_kernel<<<dim3(64, 8), 256, 0, stream>>>(pa, ws16);

  // 3 uniform streams: z=0 nn(masked), z=1 nc, z=2 color
  attn_kernel<<<dim3(8, 64, 3), 512, 0, stream>>>(
      Qn, Qc, Knn, VTnn, Knc, VTnc, Kn, VTn, packN, onesb,
      heads_nn, heads_nc, heads_c);

  outproj_kernel<<<dim3(128, 2), 256, 0, stream>>>(heads_nn, heads_nc, heads_c,
                                                   W[8], W[9], (float*)d_out);
}